// Round 14
// baseline (190.719 us; speedup 1.0000x reference)
//
#include <hip/hip_runtime.h>
#include <hip/hip_bf16.h>

using bf16 = __hip_bfloat16;
using bf16x8 = __attribute__((ext_vector_type(8))) short;
using f32x4  = __attribute__((ext_vector_type(4))) float;

__device__ inline unsigned short f2bu(float f){ bf16 h = __float2bfloat16(f); return *(unsigned short*)&h; }
__device__ inline void async_cp16(const void* g, void* l){
  __builtin_amdgcn_global_load_lds((const __attribute__((address_space(1))) void*)g,
                                   (__attribute__((address_space(3))) void*)l, 16, 0, 0);
}
union BF8 { unsigned short s[8]; bf16x8 v; };

constexpr int D_ = 1024, L_ = 2048;
constexpr int CN = 384;   // Cbig row stride (floats)

// ---------------------------------------------------------------------------
// merged prep: [0,4096) mcvt (wv->Ab, wo->wo_b, pe->peb); [4096,4352) tpB;
// [4352,4608) tc (wv -> wvTb transposed bf16); [4608,4864) q+qwk -> Ab rows 1024..1039
__global__ __launch_bounds__(256) void k_prep3(const float* __restrict__ wv, const float* __restrict__ wo,
                                               const float* __restrict__ pe, const float* __restrict__ proj_w,
                                               const float* __restrict__ proj_b, const float* __restrict__ ce,
                                               const float* __restrict__ cq, const float* __restrict__ wq,
                                               const float* __restrict__ bq, const float* __restrict__ wk,
                                               unsigned short* __restrict__ Ab, unsigned short* __restrict__ wo_b,
                                               unsigned short* __restrict__ peb, unsigned short* __restrict__ Btb,
                                               unsigned short* __restrict__ wvTb){
  __shared__ float t68[64][68];
  __shared__ float t17[64][17];
  __shared__ float qL[64];
  __shared__ float red[4][64];
  const int blk = blockIdx.x;
  const int tid = threadIdx.x;
  if (blk < 4096){           // ---- mcvt
    int i = blk*256 + tid;   // float4-quad index
    const float* src; unsigned short* dst; size_t off;
    if (i < 262144)      { src = wv; dst = Ab;   off = i; }
    else if (i < 524288) { src = wo; dst = wo_b; off = i - 262144; }
    else                 { src = pe; dst = peb;  off = i - 524288; }
    float4 v = *(const float4*)(src + off*4);
    *(ushort4*)(dst + off*4) = make_ushort4(f2bu(v.x), f2bu(v.y), f2bu(v.z), f2bu(v.w));
  } else if (blk < 4352){    // ---- tpB
    const int r_ = blk - 4096;
    const int v = r_ >> 4, dd0 = (r_ & 15)*64;
    { const int r = tid >> 2, kq = tid & 3;
      float4 a = *(const float4*)(proj_w + ((size_t)(v*D_ + dd0 + r))*16 + kq*4);
      t17[r][kq*4+0]=a.x; t17[r][kq*4+1]=a.y; t17[r][kq*4+2]=a.z; t17[r][kq*4+3]=a.w; }
    __syncthreads();
    { const int k = tid >> 4, c0 = (tid & 15)*4;
      ushort4 o = make_ushort4(f2bu(t17[c0+0][k]), f2bu(t17[c0+1][k]), f2bu(t17[c0+2][k]), f2bu(t17[c0+3][k]));
      *(ushort4*)(Btb + (size_t)(v*16+k)*D_ + dd0 + c0) = o; }
    if (tid < 16){
      const int c0 = tid*4;
      float4 pb = *(const float4*)(proj_b + v*D_ + dd0 + c0);
      float4 cc = *(const float4*)(ce     + v*D_ + dd0 + c0);
      ushort4 o = make_ushort4(f2bu(pb.x+cc.x), f2bu(pb.y+cc.y), f2bu(pb.z+cc.z), f2bu(pb.w+cc.w));
      *(ushort4*)(Btb + (size_t)(256+v)*D_ + dd0 + c0) = o;
    }
  } else if (blk < 4608){    // ---- tc: wvTb[dd][d] = bf16(wv[d][dd])  (R4/R5-verified body)
    const int r2 = blk - 4352;
    const int d0 = (r2 >> 4)*64, dd0 = (r2 & 15)*64;
    const int r = tid >> 2, c0 = (tid & 3)*16;
    #pragma unroll
    for (int j=0;j<4;++j){
      float4 v = *(const float4*)(wv + (size_t)(d0+r)*D_ + dd0 + c0 + 4*j);
      t68[r][c0+4*j+0] = v.x; t68[r][c0+4*j+1] = v.y; t68[r][c0+4*j+2] = v.z; t68[r][c0+4*j+3] = v.w;
    }
    __syncthreads();
    #pragma unroll
    for (int j=0;j<4;++j){
      ushort4 o = make_ushort4(f2bu(t68[c0+4*j+0][r]), f2bu(t68[c0+4*j+1][r]),
                               f2bu(t68[c0+4*j+2][r]), f2bu(t68[c0+4*j+3][r]));
      *(ushort4*)(wvTb + (size_t)(dd0+r)*D_ + d0 + c0 + 4*j) = o;
    }
  } else {                   // ---- q (in-LDS) + qwk -> Ab row 1024+hh
    const int b = blk - 4608;
    const int hh = b >> 4, dq = b & 15;
    const int wave = tid >> 6, lane = tid & 63;
    {
      float cqv[16];
      #pragma unroll
      for (int k=0;k<16;++k) cqv[k] = cq[lane + 64*k];
      #pragma unroll
      for (int j=0;j<16;++j){
        const int e = hh*64 + wave*16 + j;
        const float* wr = wq + (size_t)e*D_;
        float p = 0.f;
        #pragma unroll
        for (int k=0;k<16;++k) p += cqv[k]*wr[lane + 64*k];
        #pragma unroll
        for (int m=32;m>=1;m>>=1) p += __shfl_xor(p, m, 64);
        if (lane==0) qL[wave*16+j] = p + bq[e];
      }
    }
    __syncthreads();
    {
      const int eg = wave, dl = lane;
      const int d = dq*64 + dl;
      float s = 0.f;
      #pragma unroll
      for (int j=0;j<16;++j){
        int e = hh*64 + eg*16 + j;
        s += qL[eg*16+j]*wk[(size_t)e*D_ + d];
      }
      red[eg][dl] = s;
      __syncthreads();
      if (eg==0)
        Ab[(size_t)(1024+hh)*D_ + d] = f2bu(((red[0][dl]+red[1][dl]) + (red[2][dl]+red[3][dl]))*0.125f);
    }
  }
}

// ---------------------------------------------------------------------------
// GEMM body: BM=64, BN=128, BK=64; 4 waves, wave tile 32x64.
// LDS slot swizzle ^(row&7) (R10-R13 verified). BOUT: bf16 store to W instead of fp32 C.
template<bool BIAS, bool WB2, bool BOUT>
__device__ inline void gemm64_body3(unsigned short* As, unsigned short* Bs,
                                    const unsigned short* __restrict__ A, const unsigned short* __restrict__ Bt,
                                    const float* __restrict__ bias, float* __restrict__ C,
                                    unsigned short* __restrict__ W,
                                    int m0, int n0, int K, int ldc, int Mvalid){
  const int tid = threadIdx.x;
  const int wave = tid >> 6, lane = tid & 63;
  const int wm = wave & 1, wn = wave >> 1;
  const int lm = lane & 15, kg4 = lane >> 4;
  f32x4 acc[2][4];
  #pragma unroll
  for (int mf=0;mf<2;++mf)
    #pragma unroll
    for (int nf=0;nf<4;++nf) acc[mf][nf] = (f32x4){0.f,0.f,0.f,0.f};
  for (int k0=0; k0<K; k0+=64){
    #pragma unroll
    for (int i=0;i<2;++i){
      int idx = i*256 + tid;
      int row = idx >> 3, g = (idx & 7) ^ (row & 7);
      async_cp16(A + (size_t)(m0+row)*K + k0 + g*8, &As[idx*8]);
    }
    #pragma unroll
    for (int i=0;i<4;++i){
      int idx = i*256 + tid;
      int row = idx >> 3, g = (idx & 7) ^ (row & 7);
      async_cp16(Bt + (size_t)(n0+row)*K + k0 + g*8, &Bs[idx*8]);
    }
    __syncthreads();
    #pragma unroll
    for (int c=0;c<2;++c){
      bf16x8 af[2], bfr[4];
      #pragma unroll
      for (int f=0;f<2;++f){
        int row = wm*32 + f*16 + lm;
        af[f] = *(const bf16x8*)(&As[row*64 + (((c*4+kg4) ^ (row&7)))*8]);
      }
      #pragma unroll
      for (int f=0;f<4;++f){
        int colr = wn*64 + f*16 + lm;
        bfr[f] = *(const bf16x8*)(&Bs[colr*64 + (((c*4+kg4) ^ (colr&7)))*8]);
      }
      #pragma unroll
      for (int mf=0;mf<2;++mf)
        #pragma unroll
        for (int nf=0;nf<4;++nf)
          acc[mf][nf] = __builtin_amdgcn_mfma_f32_16x16x32_bf16(af[mf], bfr[nf], acc[mf][nf], 0,0,0);
    }
    __syncthreads();
  }
  #pragma unroll
  for (int nf=0;nf<4;++nf){
    int col = n0 + wn*64 + nf*16 + lm;
    float bval = BIAS ? bias[col] : 0.f;
    #pragma unroll
    for (int mf=0;mf<2;++mf){
      #pragma unroll
      for (int r=0;r<4;++r){
        int row = m0 + wm*32 + mf*16 + kg4*4 + r;
        if (row < Mvalid){
          float v = acc[mf][nf][r];
          if (BOUT){
            W[(size_t)row*ldc + col] = f2bu(v);
          } else {
            C[(size_t)row*ldc + col] = v + bval;
            if (WB2 && row < 1024 && col < 256) W[(size_t)row*256 + col] = f2bu(v);
          }
        }
      }
    }
  }
}

// merged: [0,51) Cbig (+Wb2 side-write); [51,179) W2b = wo_b · wvTb^T (bf16 out)
__global__ __launch_bounds__(256) void k_gemmCW(const unsigned short* __restrict__ Ab,
                                                const unsigned short* __restrict__ Btb,
                                                const unsigned short* __restrict__ wo_b,
                                                const unsigned short* __restrict__ wvTb,
                                                float* __restrict__ Cbig, unsigned short* __restrict__ Wb2,
                                                unsigned short* __restrict__ W2b){
  __shared__ unsigned short As[64*64];
  __shared__ unsigned short Bs[128*64];
  if (blockIdx.x < 51){
    int bx = blockIdx.x % 3, by = blockIdx.x / 3;
    gemm64_body3<false,true,false>(As, Bs, Ab, Btb, nullptr, Cbig, Wb2, by*64, bx*128, 1024, CN, 1040);
  } else {
    int b = blockIdx.x - 51;
    int bx = b & 7, by = b >> 3;
    gemm64_body3<false,false,true>(As, Bs, wo_b, wvTb, nullptr, nullptr, W2b, by*64, bx*128, 1024, 1024, 1024);
  }
}

// out cat-GEMM: out[4096][1024] = ctxF·wo_b^T + peb·W2b^T + bo ; grid (8,64)
__global__ __launch_bounds__(256) void k_gemmOutCat(const unsigned short* __restrict__ ctxF,
                                                    const unsigned short* __restrict__ wo_b,
                                                    const unsigned short* __restrict__ peb,
                                                    const unsigned short* __restrict__ W2b,
                                                    const float* __restrict__ bo, float* __restrict__ C){
  __shared__ unsigned short As[64*64];
  __shared__ unsigned short Bs[128*64];
  const int tid = threadIdx.x;
  const int wave = tid >> 6, lane = tid & 63;
  const int wm = wave & 1, wn = wave >> 1;
  const int m0 = blockIdx.y*64, n0 = blockIdx.x*128;
  const int lm = lane & 15, kg4 = lane >> 4;
  f32x4 acc[2][4];
  #pragma unroll
  for (int mf=0;mf<2;++mf)
    #pragma unroll
    for (int nf=0;nf<4;++nf) acc[mf][nf] = (f32x4){0.f,0.f,0.f,0.f};
  for (int k0=0; k0<2048; k0+=64){
    const bool first = (k0 < 1024);
    const int kk = first ? k0 : (k0 - 1024);
    #pragma unroll
    for (int i=0;i<2;++i){
      int idx = i*256 + tid;
      int row = idx >> 3, g = (idx & 7) ^ (row & 7);
      const unsigned short* ap = first ? (ctxF + (size_t)(m0+row)*1024)
                                       : (peb + (size_t)((m0+row)&2047)*1024);
      async_cp16(ap + kk + g*8, &As[idx*8]);
    }
    #pragma unroll
    for (int i=0;i<4;++i){
      int idx = i*256 + tid;
      int row = idx >> 3, g = (idx & 7) ^ (row & 7);
      const unsigned short* bp = first ? wo_b : W2b;
      async_cp16(bp + (size_t)(n0+row)*1024 + kk + g*8, &Bs[idx*8]);
    }
    __syncthreads();
    #pragma unroll
    for (int c=0;c<2;++c){
      bf16x8 af[2], bfr[4];
      #pragma unroll
      for (int f=0;f<2;++f){
        int row = wm*32 + f*16 + lm;
        af[f] = *(const bf16x8*)(&As[row*64 + (((c*4+kg4) ^ (row&7)))*8]);
      }
      #pragma unroll
      for (int f=0;f<4;++f){
        int colr = wn*64 + f*16 + lm;
        bfr[f] = *(const bf16x8*)(&Bs[colr*64 + (((c*4+kg4) ^ (colr&7)))*8]);
      }
      #pragma unroll
      for (int mf=0;mf<2;++mf)
        #pragma unroll
        for (int nf=0;nf<4;++nf)
          acc[mf][nf] = __builtin_amdgcn_mfma_f32_16x16x32_bf16(af[mf], bfr[nf], acc[mf][nf], 0,0,0);
    }
    __syncthreads();
  }
  #pragma unroll
  for (int nf=0;nf<4;++nf){
    int col = n0 + wn*64 + nf*16 + lm;
    float bval = bo[col];
    #pragma unroll
    for (int mf=0;mf<2;++mf){
      #pragma unroll
      for (int r=0;r<4;++r){
        int row = m0 + wm*32 + mf*16 + kg4*4 + r;
        C[(size_t)row*1024 + col] = acc[mf][nf][r] + bval;
      }
    }
  }
}

// ---------------------------------------------------------------------------
// fused8: 512 blocks = (bb)x(sg 128)x(hq); coalesced phase A; 2-head it-loop; no P2.
// Per-thread math identical to verified R8-R13 chain (minus the P2 add).
__global__ __launch_bounds__(256) void k_fused8(const float* __restrict__ x,
                                                const float* __restrict__ Cbig,
                                                const unsigned short* __restrict__ Wb2,
                                                const float* __restrict__ bv,
                                                unsigned short* __restrict__ ctxF){
  __shared__ float patchP[16*260];   // [s][v*16+k]
  __shared__ float attnT[8*320];     // [h8][s*20+v]
  const int tid = threadIdx.x;
  const int bb = blockIdx.x >> 8;
  const int sg = (blockIdx.x >> 1) & 127;
  const int hq = blockIdx.x & 1;
  unsigned short* ctx = ctxF + (size_t)bb*L_*D_;
  const int l0 = sg*16;
  { // phase A: thread (v, u), coalesced float4 loads (R13-verified)
    const int v = tid >> 4, u = tid & 15;
    const int hi = l0 >> 6, wi0 = l0 & 63;
    const float* xp = x + ((size_t)((bb*16+v)*128 + hi*4)*256 + (wi0+u)*4);
    float* dst = &patchP[u*260 + v*16];
    #pragma unroll
    for (int pi=0; pi<4; ++pi){
      float4 r = *(const float4*)(xp + pi*256);
      dst[pi*4+0]=r.x; dst[pi*4+1]=r.y; dst[pi*4+2]=r.z; dst[pi*4+3]=r.w;
    }
  }
  __syncthreads();
  if (tid < 128){ // phase B (R12-verified)
    const int s = tid >> 3, h8 = tid & 7;
    const int hh = hq*8 + h8;
    const float* qrow = Cbig + (size_t)(1024+hh)*CN;
    const float* prow = &patchP[s*260];
    float sc[16];
    #pragma unroll
    for (int v=0; v<16; ++v){
      float a = qrow[256+v];
      const float* qp = qrow + v*16;
      const float* pp = prow + v*16;
      #pragma unroll
      for (int k=0;k<16;++k) a += qp[k]*pp[k];
      sc[v] = a;
    }
    float mx = sc[0];
    #pragma unroll
    for (int v=1;v<16;++v) mx = fmaxf(mx, sc[v]);
    float sum = 0.f;
    #pragma unroll
    for (int v=0;v<16;++v){ sc[v] = __expf(sc[v]-mx); sum += sc[v]; }
    float inv = 1.f/sum;
    float* arow = &attnT[h8*320 + s*20];
    #pragma unroll
    for (int v=0;v<16;++v) arow[v] = sc[v]*inv;
  }
  __syncthreads();
  // phase C (R12-verified, minus P2)
  const int wave = tid >> 6, lane = tid & 63;
  const int m = lane & 15, quad = lane >> 4;
  #pragma unroll
  for (int it=0; it<2; ++it){
    const int h8 = wave*2 + it;
    const int hh = hq*8 + h8;
    const float* at = &attnT[h8*320];
    f32x4 acc[4];
    #pragma unroll
    for (int dt=0;dt<4;++dt) acc[dt] = (f32x4){0.f,0.f,0.f,0.f};
    #pragma unroll
    for (int vp=0; vp<8; ++vp){
      const int v = vp*2 + (quad>>1);
      const int k8 = (quad&1)*8;
      const float aw = at[m*20 + v];
      const float* pp = &patchP[m*260 + v*16 + k8];
      BF8 af;
      #pragma unroll
      for (int j=0;j<8;++j) af.s[j] = f2bu(aw*pp[j]);
      #pragma unroll
      for (int dt=0; dt<4; ++dt){
        const int d = hh*64 + dt*16 + m;
        const bf16x8 bf = *(const bf16x8*)(Wb2 + (size_t)d*256 + vp*32 + quad*8);
        acc[dt] = __builtin_amdgcn_mfma_f32_16x16x32_bf16(af.v, bf, acc[dt], 0,0,0);
      }
    }
    #pragma unroll
    for (int dt=0; dt<4; ++dt){
      const int d = hh*64 + dt*16 + m;
      const float* c0p = Cbig + (size_t)d*CN + 256;
      float c0v[16];
      #pragma unroll
      for (int j=0;j<4;++j){
        float4 t = *(const float4*)(c0p + 4*j);
        c0v[4*j+0]=t.x; c0v[4*j+1]=t.y; c0v[4*j+2]=t.z; c0v[4*j+3]=t.w;
      }
      const float bvd = bv[d];
      #pragma unroll
      for (int r=0;r<4;++r){
        const int s = quad*4 + r;
        float dot = bvd;   // sum_v attn = 1
        const float* as_ = at + s*20;
        #pragma unroll
        for (int v=0;v<16;++v) dot += as_[v]*c0v[v];
        ctx[(size_t)(l0+s)*D_ + d] = f2bu(acc[dt][r] + dot);
      }
    }
  }
}

// ---------------------------------------------------------------------------
extern "C" void kernel_launch(void* const* d_in, const int* in_sizes, int n_in,
                              void* d_out, int out_size, void* d_ws, size_t ws_size,
                              hipStream_t stream){
  const float* x      = (const float*)d_in[0];
  const float* proj_w = (const float*)d_in[1];
  const float* proj_b = (const float*)d_in[2];
  const float* ce     = (const float*)d_in[3];
  const float* pe     = (const float*)d_in[4];
  const float* cq     = (const float*)d_in[5];
  const float* wq     = (const float*)d_in[6];
  const float* wk     = (const float*)d_in[7];
  const float* wv     = (const float*)d_in[8];
  const float* bq     = (const float*)d_in[9];
  // bk (d_in[10]) cancels in softmax
  const float* bv     = (const float*)d_in[11];
  const float* wo     = (const float*)d_in[12];
  const float* bo     = (const float*)d_in[13];
  float* out = (float*)d_out;

  // workspace — flat, ~24.1 MB used (ws ≈ 268 MB)
  char* base = (char*)d_ws;
  unsigned short* Ab   = (unsigned short*)(base);              // [1152][1024] bf16 -> 2,359,296
  unsigned short* Btb  = (unsigned short*)(base + 2359296);    // [384][1024] bf16 -> 3,145,728
  float*          Cbig = (float*)(base + 3145728);             // [1040][384] f32 -> 4,743,168
  unsigned short* wo_b = (unsigned short*)(base + 4743168);    // [1024][1024] bf16 -> 6,840,320
  unsigned short* Wb2  = (unsigned short*)(base + 6840320);    // [1024][256] bf16 -> 7,364,608
  unsigned short* wvTb = (unsigned short*)(base + 7364608);    // [1024][1024] bf16 -> 9,461,760
  unsigned short* W2b  = (unsigned short*)(base + 9461760);    // [1024][1024] bf16 -> 11,558,912
  unsigned short* peb  = (unsigned short*)(base + 11558912);   // [2048][1024] bf16 -> 15,753,216
  unsigned short* ctxF = (unsigned short*)(base + 15753216);   // [4096][1024] bf16 -> 24,141,824

  // 1) prep: mcvt | tpB | tc | q+qwk
  k_prep3<<<4864, 256, 0, stream>>>(wv, wo, pe, proj_w, proj_b, ce, cq, wq, bq, wk,
                                    Ab, wo_b, peb, Btb, wvTb);
  // 2) Cbig (+Wb2)  ||  W2 = wo·wv (bf16)
  k_gemmCW<<<179, 256, 0, stream>>>(Ab, Btb, wo_b, wvTb, Cbig, Wb2, W2b);
  // 3) fused attention -> ctxF (both batches; x read 2x, no P2)
  k_fused8<<<512, 256, 0, stream>>>(x, Cbig, Wb2, bv, ctxF);
  // 4) out = [ctxF | pe]·[wo | W2]^T + bo   (K = 2048 cat)
  k_gemmOutCat<<<dim3(8,64), 256, 0, stream>>>(ctxF, wo_b, peb, W2b, bo, out);
}

// Round 16
// 187.366 us; speedup vs baseline: 1.0179x; 1.0179x over previous
//
#include <hip/hip_runtime.h>
#include <hip/hip_bf16.h>

using bf16 = __hip_bfloat16;
using bf16x8 = __attribute__((ext_vector_type(8))) short;
using f32x4  = __attribute__((ext_vector_type(4))) float;

__device__ inline unsigned short f2bu(float f){ bf16 h = __float2bfloat16(f); return *(unsigned short*)&h; }
__device__ inline void async_cp16(const void* g, void* l){
  __builtin_amdgcn_global_load_lds((const __attribute__((address_space(1))) void*)g,
                                   (__attribute__((address_space(3))) void*)l, 16, 0, 0);
}
union BF8 { unsigned short s[8]; bf16x8 v; };

constexpr int D_ = 1024, L_ = 2048;
constexpr int CN = 384;   // Cbig row stride (floats)

// ---------------------------------------------------------------------------
// merged prep (R13-verified): [0,2048) mcvt (wv->Ab, wo->wo_b);
// [2048,2304) tpB; [2304,2560) q+qwk -> Ab rows 1024..1039
__global__ __launch_bounds__(256) void k_prep2(const float* __restrict__ wv, const float* __restrict__ wo,
                                               const float* __restrict__ proj_w, const float* __restrict__ proj_b,
                                               const float* __restrict__ ce, const float* __restrict__ cq,
                                               const float* __restrict__ wq, const float* __restrict__ bq,
                                               const float* __restrict__ wk,
                                               unsigned short* __restrict__ Ab, unsigned short* __restrict__ wo_b,
                                               unsigned short* __restrict__ Btb){
  __shared__ float t[64][17];
  __shared__ float qL[64];
  __shared__ float red[4][64];
  const int blk = blockIdx.x;
  const int tid = threadIdx.x;
  if (blk < 2048){           // ---- mcvt
    int i = blk*256 + tid;   // float4-quad index
    const float* src; unsigned short* dst; size_t off;
    if (i < 262144){ src = wv; dst = Ab;   off = i; }
    else           { src = wo; dst = wo_b; off = i - 262144; }
    float4 v = *(const float4*)(src + off*4);
    *(ushort4*)(dst + off*4) = make_ushort4(f2bu(v.x), f2bu(v.y), f2bu(v.z), f2bu(v.w));
  } else if (blk < 2304){    // ---- tpB
    const int r_ = blk - 2048;
    const int v = r_ >> 4, dd0 = (r_ & 15)*64;
    { const int r = tid >> 2, kq = tid & 3;
      float4 a = *(const float4*)(proj_w + ((size_t)(v*D_ + dd0 + r))*16 + kq*4);
      t[r][kq*4+0]=a.x; t[r][kq*4+1]=a.y; t[r][kq*4+2]=a.z; t[r][kq*4+3]=a.w; }
    __syncthreads();
    { const int k = tid >> 4, c0 = (tid & 15)*4;
      ushort4 o = make_ushort4(f2bu(t[c0+0][k]), f2bu(t[c0+1][k]), f2bu(t[c0+2][k]), f2bu(t[c0+3][k]));
      *(ushort4*)(Btb + (size_t)(v*16+k)*D_ + dd0 + c0) = o; }
    if (tid < 16){
      const int c0 = tid*4;
      float4 pb = *(const float4*)(proj_b + v*D_ + dd0 + c0);
      float4 cc = *(const float4*)(ce     + v*D_ + dd0 + c0);
      ushort4 o = make_ushort4(f2bu(pb.x+cc.x), f2bu(pb.y+cc.y), f2bu(pb.z+cc.z), f2bu(pb.w+cc.w));
      *(ushort4*)(Btb + (size_t)(256+v)*D_ + dd0 + c0) = o;
    }
  } else {                   // ---- q (in-LDS) + qwk -> Ab row 1024+hh
    const int b = blk - 2304;
    const int hh = b >> 4, dq = b & 15;
    const int wave = tid >> 6, lane = tid & 63;
    {
      float cqv[16];
      #pragma unroll
      for (int k=0;k<16;++k) cqv[k] = cq[lane + 64*k];
      #pragma unroll
      for (int j=0;j<16;++j){
        const int e = hh*64 + wave*16 + j;
        const float* wr = wq + (size_t)e*D_;
        float p = 0.f;
        #pragma unroll
        for (int k=0;k<16;++k) p += cqv[k]*wr[lane + 64*k];
        #pragma unroll
        for (int m=32;m>=1;m>>=1) p += __shfl_xor(p, m, 64);
        if (lane==0) qL[wave*16+j] = p + bq[e];
      }
    }
    __syncthreads();
    {
      const int eg = wave, dl = lane;
      const int d = dq*64 + dl;
      float s = 0.f;
      #pragma unroll
      for (int j=0;j<16;++j){
        int e = hh*64 + eg*16 + j;
        s += qL[eg*16+j]*wk[(size_t)e*D_ + d];
      }
      red[eg][dl] = s;
      __syncthreads();
      if (eg==0)
        Ab[(size_t)(1024+hh)*D_ + d] = f2bu(((red[0][dl]+red[1][dl]) + (red[2][dl]+red[3][dl]))*0.125f);
    }
  }
}

// ---------------------------------------------------------------------------
// GEMM body: BM = MFRAG*32, BN=128, BK=64; 4 waves (2x2), wave tile (MFRAG*16)x64.
// LDS slot swizzle ^(row&7) (R10-R13 verified). Generalized from the R13 MFRAG=2 body
// with identical indexing algebra (wm*32 == wm*16*MFRAG at MFRAG=2).
template<int MFRAG, bool AFP32, bool BIAS, bool WB2>
__device__ inline void gemm_body(unsigned short* As, unsigned short* Bs,
                                 const void* __restrict__ Av, const unsigned short* __restrict__ Bt,
                                 const float* __restrict__ bias, float* __restrict__ C,
                                 unsigned short* __restrict__ W,
                                 int m0, int n0, int K, int ldc, int Mvalid){
  const int tid = threadIdx.x;
  const int wave = tid >> 6, lane = tid & 63;
  const int wm = wave & 1, wn = wave >> 1;
  const int lm = lane & 15, kg4 = lane >> 4;
  const unsigned short* Abf = (const unsigned short*)Av;
  const float* Afp = (const float*)Av;
  f32x4 acc[MFRAG][4];
  #pragma unroll
  for (int mf=0;mf<MFRAG;++mf)
    #pragma unroll
    for (int nf=0;nf<4;++nf) acc[mf][nf] = (f32x4){0.f,0.f,0.f,0.f};
  for (int k0=0; k0<K; k0+=64){
    #pragma unroll
    for (int i=0;i<MFRAG;++i){
      int idx = i*256 + tid;
      int row = idx >> 3, g = (idx & 7) ^ (row & 7);
      if (!AFP32){
        async_cp16(Abf + (size_t)(m0+row)*K + k0 + g*8, &As[idx*8]);
      } else {
        const float* gp = Afp + (size_t)(m0+row)*K + k0 + g*8;
        float4 a0 = *(const float4*)gp, a1 = *(const float4*)(gp+4);
        *(ushort4*)(&As[idx*8])   = make_ushort4(f2bu(a0.x),f2bu(a0.y),f2bu(a0.z),f2bu(a0.w));
        *(ushort4*)(&As[idx*8+4]) = make_ushort4(f2bu(a1.x),f2bu(a1.y),f2bu(a1.z),f2bu(a1.w));
      }
    }
    #pragma unroll
    for (int i=0;i<4;++i){
      int idx = i*256 + tid;
      int row = idx >> 3, g = (idx & 7) ^ (row & 7);
      async_cp16(Bt + (size_t)(n0+row)*K + k0 + g*8, &Bs[idx*8]);
    }
    __syncthreads();
    #pragma unroll
    for (int c=0;c<2;++c){
      bf16x8 af[MFRAG], bfr[4];
      #pragma unroll
      for (int f=0;f<MFRAG;++f){
        int row = wm*16*MFRAG + f*16 + lm;
        af[f] = *(const bf16x8*)(&As[row*64 + (((c*4+kg4) ^ (row&7)))*8]);
      }
      #pragma unroll
      for (int f=0;f<4;++f){
        int colr = wn*64 + f*16 + lm;
        bfr[f] = *(const bf16x8*)(&Bs[colr*64 + (((c*4+kg4) ^ (colr&7)))*8]);
      }
      #pragma unroll
      for (int mf=0;mf<MFRAG;++mf)
        #pragma unroll
        for (int nf=0;nf<4;++nf)
          acc[mf][nf] = __builtin_amdgcn_mfma_f32_16x16x32_bf16(af[mf], bfr[nf], acc[mf][nf], 0,0,0);
    }
    __syncthreads();
  }
  #pragma unroll
  for (int nf=0;nf<4;++nf){
    int col = n0 + wn*64 + nf*16 + lm;
    float bval = BIAS ? bias[col] : 0.f;
    #pragma unroll
    for (int mf=0;mf<MFRAG;++mf){
      #pragma unroll
      for (int r=0;r<4;++r){
        int row = m0 + wm*16*MFRAG + mf*16 + kg4*4 + r;
        if (row < Mvalid){
          float v = acc[mf][nf][r];
          C[(size_t)row*ldc + col] = v + bval;
          if (WB2 && row < 1024 && col < 256) W[(size_t)row*256 + col] = f2bu(v);
        }
      }
    }
  }
}

// merged: [0,51) Cbig GEMM BM=64 (+Wb2 side-write); [51,563) P2 GEMM BM=32 (pe fp32-staged)
__global__ __launch_bounds__(256) void k_gemmCP2(const unsigned short* __restrict__ Ab,
                                                 const unsigned short* __restrict__ Btb,
                                                 const float* __restrict__ pe,
                                                 float* __restrict__ Cbig, unsigned short* __restrict__ Wb2,
                                                 float* __restrict__ P2){
  __shared__ unsigned short As[64*64];
  __shared__ unsigned short Bs[128*64];
  if (blockIdx.x < 51){
    int bx = blockIdx.x % 3, by = blockIdx.x / 3;
    gemm_body<2,false,false,true>(As, Bs, Ab, Btb, nullptr, Cbig, Wb2, by*64, bx*128, 1024, CN, 1040);
  } else {
    int b = blockIdx.x - 51;          // [0,512): 8 n-tiles x 64 m-tiles of 32
    int bx = b & 7, by = b >> 3;
    gemm_body<1,true,false,false>(As, Bs, pe, Ab, nullptr, P2, nullptr, by*32, bx*128, 1024, 1024, 2048);
  }
}

// out GEMM: out[4096][1024] = ctxF·wo_b^T + bo ; BM=32, grid (8,128) = 1024 blocks
__global__ __launch_bounds__(256) void k_gemmOut(const unsigned short* __restrict__ ctxF,
                                                 const unsigned short* __restrict__ wo_b,
                                                 const float* __restrict__ bo, float* __restrict__ C){
  __shared__ unsigned short As[32*64];
  __shared__ unsigned short Bs[128*64];
  gemm_body<1,false,true,false>(As, Bs, ctxF, wo_b, bo, C, nullptr,
                                blockIdx.y*32, blockIdx.x*128, 1024, 1024, 4096);
}

// ---------------------------------------------------------------------------
// fused v7 (R13-verified, byte-identical): grid 1024 = (bb) x (sg 128) x (hqq 2b).
__global__ __launch_bounds__(256) void k_fused7(const float* __restrict__ x,
                                                const float* __restrict__ Cbig,
                                                const unsigned short* __restrict__ Wb2,
                                                const float* __restrict__ bv,
                                                const float* __restrict__ P2,
                                                unsigned short* __restrict__ ctxF){
  __shared__ float patchP[16*260];   // [s][v*16+k]
  __shared__ float attnT[4*320];     // [h4][s*20+v]
  const int tid = threadIdx.x;
  const int bb  = blockIdx.x >> 9;
  const int sg  = (blockIdx.x >> 2) & 127;
  const int hqq = blockIdx.x & 3;
  unsigned short* ctx = ctxF + (size_t)bb*L_*D_;
  const int l0 = sg*16;
  { // phase A: thread (v, u): coalesced float4 loads
    const int v = tid >> 4, u = tid & 15;
    const int hi = l0 >> 6, wi0 = l0 & 63;
    const float* xp = x + ((size_t)((bb*16+v)*128 + hi*4)*256 + (wi0+u)*4);
    float* dst = &patchP[u*260 + v*16];
    #pragma unroll
    for (int pi=0; pi<4; ++pi){
      float4 r = *(const float4*)(xp + pi*256);
      dst[pi*4+0]=r.x; dst[pi*4+1]=r.y; dst[pi*4+2]=r.z; dst[pi*4+3]=r.w;
    }
  }
  __syncthreads();
  if (tid < 64){ // phase B: thread (s, h4): scores + softmax -> attnT
    const int s = tid >> 2, h4 = tid & 3;
    const int hh = hqq*4 + h4;
    const float* qrow = Cbig + (size_t)(1024+hh)*CN;
    const float* prow = &patchP[s*260];
    float sc[16];
    #pragma unroll
    for (int v=0; v<16; ++v){
      float a = qrow[256+v];
      const float* qp = qrow + v*16;
      const float* pp = prow + v*16;
      #pragma unroll
      for (int k=0;k<16;++k) a += qp[k]*pp[k];
      sc[v] = a;
    }
    float mx = sc[0];
    #pragma unroll
    for (int v=1;v<16;++v) mx = fmaxf(mx, sc[v]);
    float sum = 0.f;
    #pragma unroll
    for (int v=0;v<16;++v){ sc[v] = __expf(sc[v]-mx); sum += sc[v]; }
    float inv = 1.f/sum;
    float* arow = &attnT[h4*320 + s*20];
    #pragma unroll
    for (int v=0;v<16;++v) arow[v] = sc[v]*inv;
  }
  __syncthreads();
  // phase C: wave = head
  const int wave = tid >> 6, lane = tid & 63;
  const int m = lane & 15, quad = lane >> 4;
  const int hh = hqq*4 + wave;
  const float* at = &attnT[wave*320];
  f32x4 acc[4];
  #pragma unroll
  for (int dt=0;dt<4;++dt) acc[dt] = (f32x4){0.f,0.f,0.f,0.f};
  #pragma unroll
  for (int vp=0; vp<8; ++vp){
    const int v = vp*2 + (quad>>1);
    const int k8 = (quad&1)*8;
    const float aw = at[m*20 + v];
    const float* pp = &patchP[m*260 + v*16 + k8];
    BF8 af;
    #pragma unroll
    for (int j=0;j<8;++j) af.s[j] = f2bu(aw*pp[j]);
    #pragma unroll
    for (int dt=0; dt<4; ++dt){
      const int d = hh*64 + dt*16 + m;
      const bf16x8 bf = *(const bf16x8*)(Wb2 + (size_t)d*256 + vp*32 + quad*8);
      acc[dt] = __builtin_amdgcn_mfma_f32_16x16x32_bf16(af.v, bf, acc[dt], 0,0,0);
    }
  }
  #pragma unroll
  for (int dt=0; dt<4; ++dt){
    const int d = hh*64 + dt*16 + m;
    const float* c0p = Cbig + (size_t)d*CN + 256;
    float c0v[16];
    #pragma unroll
    for (int j=0;j<4;++j){
      float4 t = *(const float4*)(c0p + 4*j);
      c0v[4*j+0]=t.x; c0v[4*j+1]=t.y; c0v[4*j+2]=t.z; c0v[4*j+3]=t.w;
    }
    const float bvd = bv[d];
    #pragma unroll
    for (int r=0;r<4;++r){
      const int s = quad*4 + r;
      float dot = bvd;   // sum_v attn = 1
      const float* as_ = at + s*20;
      #pragma unroll
      for (int v=0;v<16;++v) dot += as_[v]*c0v[v];
      ctx[(size_t)(l0+s)*D_ + d] = f2bu(acc[dt][r] + dot + P2[(size_t)(l0+s)*D_ + d]);
    }
  }
}

// ---------------------------------------------------------------------------
extern "C" void kernel_launch(void* const* d_in, const int* in_sizes, int n_in,
                              void* d_out, int out_size, void* d_ws, size_t ws_size,
                              hipStream_t stream){
  const float* x      = (const float*)d_in[0];
  const float* proj_w = (const float*)d_in[1];
  const float* proj_b = (const float*)d_in[2];
  const float* ce     = (const float*)d_in[3];
  const float* pe     = (const float*)d_in[4];
  const float* cq     = (const float*)d_in[5];
  const float* wq     = (const float*)d_in[6];
  const float* wk     = (const float*)d_in[7];
  const float* wv     = (const float*)d_in[8];
  const float* bq     = (const float*)d_in[9];
  // bk (d_in[10]) cancels in softmax
  const float* bv     = (const float*)d_in[11];
  const float* wo     = (const float*)d_in[12];
  const float* bo     = (const float*)d_in[13];
  float* out = (float*)d_out;

  // workspace — flat, ~24.1 MB used (ws ≈ 268 MB measured via poison-fill WRITE_SIZE)
  char* base = (char*)d_ws;
  unsigned short* Ab   = (unsigned short*)(base);              // [1152][1024] bf16 -> 2,359,296
  unsigned short* Btb  = (unsigned short*)(base + 2359296);    // [384][1024] bf16 -> 3,145,728
  float*          Cbig = (float*)(base + 3145728);             // [1040][384] f32 -> 4,743,168
  unsigned short* wo_b = (unsigned short*)(base + 4743168);    // [1024][1024] bf16 -> 6,840,320
  unsigned short* Wb2  = (unsigned short*)(base + 6840320);    // [1024][256] bf16 -> 7,364,608
  float*          P2   = (float*)(base + 7364608);             // [2048][1024] f32 -> 15,753,216
  unsigned short* ctxF = (unsigned short*)(base + 15753216);   // [4096][1024] bf16 -> 24,141,824

  // 1) prep: mcvt | tpB | q+qwk
  k_prep2<<<2560, 256, 0, stream>>>(wv, wo, proj_w, proj_b, ce, cq, wq, bq, wk, Ab, wo_b, Btb);
  // 2) Cbig (+Wb2)  ||  P2 = pe·wv^T (pe fp32-staged, BM=32 -> 512 blocks)
  k_gemmCP2<<<563, 256, 0, stream>>>(Ab, Btb, pe, Cbig, Wb2, P2);
  // 3) fused attention -> ctxF (both batches; 4-head blocks, 4 blocks/CU)
  k_fused7<<<1024, 256, 0, stream>>>(x, Cbig, Wb2, bv, P2, ctxF);
  // 4) out = ctxF·wo^T + bo   (BM=32 -> 1024 blocks)
  k_gemmOut<<<dim3(8,128), 256, 0, stream>>>(ctxF, wo_b, bo, out);
}